// Round 1
// baseline (2089.400 us; speedup 1.0000x reference)
//
#include <hip/hip_runtime.h>
#include <stdint.h>
#include <math.h>

#define BATCH 32768
#define LDIM 128
#define HID 20
#define NG 80                       // 4*HID

// =====================================================================
// eps: jax.random.normal(key(42), (128,32768), f32), partitionable
// threefry (counters (0,n), output o0^o1) — VERIFIED PASSING (r4/r5,
// absmax 0.0156 = 1 bf16 ulp). Do not touch.
// =====================================================================

__device__ __forceinline__ void threefry2x32(uint32_t x0, uint32_t x1,
                                             uint32_t& o0, uint32_t& o1) {
  const uint32_t k0 = 0u, k1 = 42u;
  const uint32_t k2 = k0 ^ k1 ^ 0x1BD11BDAu;
  uint32_t v0 = x0 + k0, v1 = x1 + k1;
#define TF_R(r) { v0 += v1; v1 = (v1 << (r)) | (v1 >> (32 - (r))); v1 ^= v0; }
  TF_R(13) TF_R(15) TF_R(26) TF_R(6)
  v0 += k1; v1 += k2 + 1u;
  TF_R(17) TF_R(29) TF_R(16) TF_R(24)
  v0 += k2; v1 += k0 + 2u;
  TF_R(13) TF_R(15) TF_R(26) TF_R(6)
  v0 += k0; v1 += k1 + 3u;
  TF_R(17) TF_R(29) TF_R(16) TF_R(24)
  v0 += k1; v1 += k2 + 4u;
  TF_R(13) TF_R(15) TF_R(26) TF_R(6)
  v0 += k2; v1 += k0 + 5u;
#undef TF_R
  o0 = v0; o1 = v1;
}

__device__ __forceinline__ float erfinv_xla_f32(float x) {
  float t = __fmul_rn(x, x);
  float w = -(float)log1p(-(double)t);   // correctly-rounded f32 log1p
  float p;
  if (w < 5.0f) {
    w = __fadd_rn(w, -2.5f);
    p = 2.81022636e-08f;
    p = __fadd_rn(__fmul_rn(p, w), 3.43273939e-07f);
    p = __fadd_rn(__fmul_rn(p, w), -3.5233877e-06f);
    p = __fadd_rn(__fmul_rn(p, w), -4.39150654e-06f);
    p = __fadd_rn(__fmul_rn(p, w), 0.00021858087f);
    p = __fadd_rn(__fmul_rn(p, w), -0.00125372503f);
    p = __fadd_rn(__fmul_rn(p, w), -0.00417768164f);
    p = __fadd_rn(__fmul_rn(p, w), 0.246640727f);
    p = __fadd_rn(__fmul_rn(p, w), 1.50140941f);
  } else {
    w = __fadd_rn(__fsqrt_rn(w), -3.0f);
    p = -0.000200214257f;
    p = __fadd_rn(__fmul_rn(p, w), 0.000100950558f);
    p = __fadd_rn(__fmul_rn(p, w), 0.00134934322f);
    p = __fadd_rn(__fmul_rn(p, w), -0.00367342844f);
    p = __fadd_rn(__fmul_rn(p, w), 0.00573950773f);
    p = __fadd_rn(__fmul_rn(p, w), -0.0076224613f);
    p = __fadd_rn(__fmul_rn(p, w), 0.00943887047f);
    p = __fadd_rn(__fmul_rn(p, w), 1.00167406f);
    p = __fadd_rn(__fmul_rn(p, w), 2.83297682f);
  }
  return __fmul_rn(p, x);
}

__device__ __forceinline__ float eps_val(int t, int b) {
  uint32_t n = (uint32_t)t * 32768u + (uint32_t)b;
  uint32_t o0, o1;
  threefry2x32(0u, n, o0, o1);
  uint32_t bits = o0 ^ o1;
  const float lo    = __uint_as_float(0xBF7FFFFFu);
  const float sqrt2 = __uint_as_float(0x3FB504F3u);
  float f = __fadd_rn(__uint_as_float((bits >> 9) | 0x3F800000u), -1.0f);
  float u = __fadd_rn(__fmul_rn(f, 2.0f), lo);
  u = fmaxf(u, lo);
  return __fmul_rn(sqrt2, erfinv_xla_f32(u));
}

__device__ __forceinline__ float fexp2(float x) { return __builtin_amdgcn_exp2f(x); }
__device__ __forceinline__ float frcp(float x)  { return __builtin_amdgcn_rcpf(x); }
__device__ __forceinline__ float fexp(float x)  { return fexp2(1.442695040888963f * x); }
__device__ __forceinline__ float sigm(float x)  { return frcp(1.0f + fexp2(-1.442695040888963f * x)); }
__device__ __forceinline__ float tanhx(float x) { return 1.0f - 2.0f * frcp(1.0f + fexp2(2.885390081777926f * x)); }

// 4 lanes per element: role = tid&3 owns k in [5*role, 5*role+5) (20 gates).
// 131072 threads = 2048 waves = 2 waves/SIMD (was 1) — latency hiding.
__global__ __launch_bounds__(256, 2) void sampler_kernel(
    const float* __restrict__ mu, const float* __restrict__ log_var,
    const float* __restrict__ W_ih1, const float* __restrict__ W_hh1,
    const float* __restrict__ b_ih1, const float* __restrict__ b_hh1,
    const float* __restrict__ W_ih2, const float* __restrict__ W_hh2,
    const float* __restrict__ b_ih2, const float* __restrict__ b_hh2,
    float* __restrict__ out) {
  // role-split layouts: per-instruction only 4 distinct LDS addresses
  // (16-lane broadcast each); worst bank aliasing is 2-way (free, m136).
  __shared__ __align__(16) float sWih1T[127 * NG];  // [j][role*20 + type*5 + kl]
  __shared__ __align__(16) float sWhh1[NG * HID];   // [((role*4+type)*5+kl)][j]
  __shared__ __align__(16) float sWih2[320];        // [((role*5+kl)*2+hc)][j=0..7]
  __shared__ __align__(16) float sB1s[NG];          // [role*20 + type*5 + kl]
  __shared__ __align__(16) float sH[64 * HID];      // per-elem h exchange buffer

  const int tid = threadIdx.x;
  for (int i = tid; i < 127 * NG; i += 256) {
    int j = i / NG, q = i - j * NG;          // q = role*20 + type*5 + kl
    int ro = q / 20, rem = q - ro * 20;
    int ty = rem / 5, kl = rem - ty * 5;
    int g = ty * 20 + ro * 5 + kl;
    sWih1T[i] = W_ih1[g * 127 + j];
  }
  for (int i = tid; i < NG * HID; i += 256) {
    int j = i % HID, r = i / HID;            // r = (role*4+type)*5+kl
    int kl = r % 5, rt = r / 5;
    int ro = rt >> 2, ty = rt & 3;
    int g = ty * 20 + ro * 5 + kl;
    sWhh1[i] = W_hh1[g * HID + j];
  }
  for (int i = tid; i < 320; i += 256) {
    int j = i & 7, r = i >> 3;               // r = (role*5+kl)*2+hc
    int hc = r & 1, rk = r >> 1;
    int ro = rk / 5, kl = rk - ro * 5;
    sWih2[i] = W_ih2[j * 40 + hc * 20 + ro * 5 + kl];
  }
  if (tid < NG) {
    int ro = tid / 20, rem = tid % 20;
    int ty = rem / 5, kl = rem % 5;
    int g = ty * 20 + ro * 5 + kl;
    sB1s[tid] = b_ih1[g] + b_hh1[g];
  }
  __syncthreads();

  // tiny LSTM2 weights: uniform loads, hoisted out of the loop entirely
  float w2[16], b2s[8];
#pragma unroll
  for (int i = 0; i < 16; ++i) w2[i] = W_hh2[i];
#pragma unroll
  for (int i = 0; i < 8; ++i)  b2s[i] = b_ih2[i] + b_hh2[i];

  const int role = tid & 3;
  const int eloc = tid >> 2;
  const int elem = blockIdx.x * 64 + eloc;
  const int rbase = role * 20;
  const float* mrow = mu + (size_t)elem * LDIM;
  float* hx = &sH[eloc * HID];

  // first_input (computed identically on all 4 lanes of the group)
  float eps0 = eps_val(0, elem);
  float m0 = mrow[0];
  float fi = fmaf(eps0, fexp(0.5f * log_var[(size_t)elem * LDIM]), m0);

  // acc[i], i = type*5+kl — this lane's 20 gate accumulators.
  // Bias (b_ih1+b_hh1) folded in at init: constant across steps, the
  // prefix updates preserve it → saves 20 LDS reads + 20 adds per step.
  float acc[20];
  {
    const float4* c4 = (const float4*)&sWih1T[rbase];
    const float4* b4 = (const float4*)&sB1s[rbase];
#pragma unroll
    for (int q = 0; q < 5; ++q) {
      float4 w4 = c4[q], bb = b4[q];
      acc[4*q]   = fmaf(fi, w4.x, bb.x);
      acc[4*q+1] = fmaf(fi, w4.y, bb.y);
      acc[4*q+2] = fmaf(fi, w4.z, bb.z);
      acc[4*q+3] = fmaf(fi, w4.w, bb.w);
    }
  }

  float h[HID], c[5];
#pragma unroll
  for (int k = 0; k < HID; ++k) h[k] = 0.0f;
#pragma unroll
  for (int k = 0; k < 5; ++k) c[k] = 0.0f;
  float h2a = 0.0f, h2b = 0.0f, c2a = 0.0f, c2b = 0.0f;

  float* out_mu = out;
  float* out_lv = out + (size_t)BATCH * LDIM;
  float* out_sp = out + 2 * (size_t)BATCH * LDIM;
  const size_t rowoff = (size_t)elem * LDIM;
  if (role == 0)      out_mu[rowoff] = 0.0f;
  else if (role == 1) out_lv[rowoff] = 1.0f;
  else if (role == 2) out_sp[rowoff] = fi;

  float xm_pref = m0;     // mrow[t-1] prefetched one iteration ahead
  float eps4 = 0.0f;      // this role's eps for t = tgroup + role

  for (int t = 1; t < LDIM; ++t) {
    const int ph = (t - 1) & 3;
    float xm = xm_pref;
    xm_pref = mrow[t];                       // for next iter: mrow[(t+1)-1]
    // eps role-split: every 4th step each role computes eps(t+role);
    // consumers fetch via shuffle — bit-identical values, 4x fewer calls.
    if (ph == 0) eps4 = eps_val(t + role, elem);

    // ---- maintain acc = bias + (input cols) @ W_ih1^T  (prefix trick) ----
    if (t >= 2) {
      if (t == 2) {
        float d0 = m0 - fi;   // col 0 switches first_input -> mu[:,0]
        const float4* c04 = (const float4*)&sWih1T[rbase];
#pragma unroll
        for (int q = 0; q < 5; ++q) {
          float4 w4 = c04[q];
          acc[4*q]   = fmaf(d0, w4.x, acc[4*q]);
          acc[4*q+1] = fmaf(d0, w4.y, acc[4*q+1]);
          acc[4*q+2] = fmaf(d0, w4.z, acc[4*q+2]);
          acc[4*q+3] = fmaf(d0, w4.w, acc[4*q+3]);
        }
      }
      const float4* col4 = (const float4*)&sWih1T[(t - 1) * NG + rbase];
#pragma unroll
      for (int q = 0; q < 5; ++q) {
        float4 w4 = col4[q];
        acc[4*q]   = fmaf(xm, w4.x, acc[4*q]);
        acc[4*q+1] = fmaf(xm, w4.y, acc[4*q+1]);
        acc[4*q+2] = fmaf(xm, w4.z, acc[4*q+2]);
        acc[4*q+3] = fmaf(xm, w4.w, acc[4*q+3]);
      }
    }

    // ---- LSTM2 gate init (replicated on all 4 lanes; all-register) ----
    float g2i[8], g2p[8];
#pragma unroll
    for (int jj = 0; jj < 8; ++jj) {
      g2i[jj] = fmaf(h2a, w2[2*jj], fmaf(h2b, w2[2*jj+1], b2s[jj]));
      g2p[jj] = 0.0f;
    }

    // ---- LSTM1: this lane's 5 k's (20 gates), fused LSTM2 partials ----
    float hn[5];
#pragma unroll
    for (int kl = 0; kl < 5; ++kl) {
      float s0 = acc[kl];
      float s1 = acc[5 + kl];
      float s2 = acc[10 + kl];
      float s3 = acc[15 + kl];
      const float4* wi = (const float4*)&sWhh1[((role * 4 + 0) * 5 + kl) * HID];
      const float4* wf = (const float4*)&sWhh1[((role * 4 + 1) * 5 + kl) * HID];
      const float4* wg = (const float4*)&sWhh1[((role * 4 + 2) * 5 + kl) * HID];
      const float4* wo = (const float4*)&sWhh1[((role * 4 + 3) * 5 + kl) * HID];
#pragma unroll
      for (int q = 0; q < 5; ++q) {
        float4 a = wi[q], bq = wf[q], cq = wg[q], dq = wo[q];
        float v0 = h[4*q], v1 = h[4*q+1], v2 = h[4*q+2], v3 = h[4*q+3];
        s0 = fmaf(v0, a.x, s0);  s0 = fmaf(v1, a.y, s0);
        s0 = fmaf(v2, a.z, s0);  s0 = fmaf(v3, a.w, s0);
        s1 = fmaf(v0, bq.x, s1); s1 = fmaf(v1, bq.y, s1);
        s1 = fmaf(v2, bq.z, s1); s1 = fmaf(v3, bq.w, s1);
        s2 = fmaf(v0, cq.x, s2); s2 = fmaf(v1, cq.y, s2);
        s2 = fmaf(v2, cq.z, s2); s2 = fmaf(v3, cq.w, s2);
        s3 = fmaf(v0, dq.x, s3); s3 = fmaf(v1, dq.y, s3);
        s3 = fmaf(v2, dq.z, s3); s3 = fmaf(v3, dq.w, s3);
      }
      float ik = sigm(s0), fk = sigm(s1), gk = tanhx(s2), ok = sigm(s3);
      float cn = fmaf(fk, c[kl], ik * gk);
      c[kl] = cn;
      float hk = ok * tanhx(cn);
      hn[kl] = hk;
      float lh = (hk >= 0.0f) ? hk : 0.01f * hk;
      float lc = (cn >= 0.0f) ? cn : 0.01f * cn;
      const float4* uu = (const float4*)&sWih2[((role * 5 + kl) * 2 + 0) * 8];
      const float4* vv = (const float4*)&sWih2[((role * 5 + kl) * 2 + 1) * 8];
      float4 u0 = uu[0], u1 = uu[1], v0 = vv[0], v1 = vv[1];
      g2p[0] = fmaf(lh, u0.x, g2p[0]); g2p[1] = fmaf(lh, u0.y, g2p[1]);
      g2p[2] = fmaf(lh, u0.z, g2p[2]); g2p[3] = fmaf(lh, u0.w, g2p[3]);
      g2p[4] = fmaf(lh, u1.x, g2p[4]); g2p[5] = fmaf(lh, u1.y, g2p[5]);
      g2p[6] = fmaf(lh, u1.z, g2p[6]); g2p[7] = fmaf(lh, u1.w, g2p[7]);
      g2p[0] = fmaf(lc, v0.x, g2p[0]); g2p[1] = fmaf(lc, v0.y, g2p[1]);
      g2p[2] = fmaf(lc, v0.z, g2p[2]); g2p[3] = fmaf(lc, v0.w, g2p[3]);
      g2p[4] = fmaf(lc, v1.x, g2p[4]); g2p[5] = fmaf(lc, v1.y, g2p[5]);
      g2p[6] = fmaf(lc, v1.z, g2p[6]); g2p[7] = fmaf(lc, v1.w, g2p[7]);
    }

    // ---- h all-gather via wave-synchronous LDS (group of 4 lanes is
    // always inside one wave; compiler inserts lgkmcnt, no barrier) ----
#pragma unroll
    for (int kl = 0; kl < 5; ++kl) hx[role * 5 + kl] = hn[kl];
    {
      const float4* h4 = (const float4*)hx;
#pragma unroll
      for (int q = 0; q < 5; ++q) {
        float4 hv = h4[q];
        h[4*q] = hv.x; h[4*q+1] = hv.y; h[4*q+2] = hv.z; h[4*q+3] = hv.w;
      }
    }

    // ---- LSTM2 gates: 4-lane butterfly reduce, then cell (replicated) ----
    float g2[8];
#pragma unroll
    for (int jj = 0; jj < 8; ++jj) {
      float v = g2p[jj];
      v += __shfl_xor(v, 1, 64);
      v += __shfl_xor(v, 2, 64);
      g2[jj] = g2i[jj] + v;
    }

    float i20 = sigm(g2[0]), i21 = sigm(g2[1]);
    float f20 = sigm(g2[2]), f21 = sigm(g2[3]);
    float t20 = tanhx(g2[4]), t21 = tanhx(g2[5]);
    float o20 = sigm(g2[6]), o21 = sigm(g2[7]);
    c2a = fmaf(f20, c2a, i20 * t20);
    c2b = fmaf(f21, c2b, i21 * t21);
    h2a = o20 * tanhx(c2a);
    h2b = o21 * tanhx(c2b);

    // ---- sample + stores (role-split) ----
    float eps_t = __shfl(eps4, (tid & 60) | ph, 64);
    float sp = fmaf(eps_t, fexp(0.5f * h2b), h2a);
    if (role == 0)      out_mu[rowoff + t] = h2a;
    else if (role == 1) out_lv[rowoff + t] = h2b;
    else if (role == 2) out_sp[rowoff + t] = sp;
  }
}

extern "C" void kernel_launch(void* const* d_in, const int* in_sizes, int n_in,
                              void* d_out, int out_size, void* d_ws, size_t ws_size,
                              hipStream_t stream) {
  (void)in_sizes; (void)n_in; (void)d_ws; (void)ws_size; (void)out_size;
  const float* mu      = (const float*)d_in[0];
  const float* log_var = (const float*)d_in[1];
  const float* W_ih1   = (const float*)d_in[2];
  const float* W_hh1   = (const float*)d_in[3];
  const float* b_ih1   = (const float*)d_in[4];
  const float* b_hh1   = (const float*)d_in[5];
  const float* W_ih2   = (const float*)d_in[6];
  const float* W_hh2   = (const float*)d_in[7];
  const float* b_ih2   = (const float*)d_in[8];
  const float* b_hh2   = (const float*)d_in[9];
  float* out = (float*)d_out;

  dim3 grid(BATCH / 64), block(256);   // 4 lanes per element, 512 blocks = 2/CU
  sampler_kernel<<<grid, block, 0, stream>>>(mu, log_var, W_ih1, W_hh1, b_ih1,
                                             b_hh1, W_ih2, W_hh2, b_ih2, b_hh2, out);
}

// Round 2
// 1090.188 us; speedup vs baseline: 1.9166x; 1.9166x over previous
//
#include <hip/hip_runtime.h>
#include <stdint.h>
#include <math.h>

#define BATCH 32768
#define LDIM 128
#define HID 20
#define NG 80                       // 4*HID

// =====================================================================
// eps: jax.random.normal(key(42), (128,32768), f32), partitionable
// threefry (counters (0,n), output o0^o1) — VERIFIED PASSING (r4/r5,
// absmax 0.0156 = 1 bf16 ulp). Do not touch.
// =====================================================================

__device__ __forceinline__ void threefry2x32(uint32_t x0, uint32_t x1,
                                             uint32_t& o0, uint32_t& o1) {
  const uint32_t k0 = 0u, k1 = 42u;
  const uint32_t k2 = k0 ^ k1 ^ 0x1BD11BDAu;
  uint32_t v0 = x0 + k0, v1 = x1 + k1;
#define TF_R(r) { v0 += v1; v1 = (v1 << (r)) | (v1 >> (32 - (r))); v1 ^= v0; }
  TF_R(13) TF_R(15) TF_R(26) TF_R(6)
  v0 += k1; v1 += k2 + 1u;
  TF_R(17) TF_R(29) TF_R(16) TF_R(24)
  v0 += k2; v1 += k0 + 2u;
  TF_R(13) TF_R(15) TF_R(26) TF_R(6)
  v0 += k0; v1 += k1 + 3u;
  TF_R(17) TF_R(29) TF_R(16) TF_R(24)
  v0 += k1; v1 += k2 + 4u;
  TF_R(13) TF_R(15) TF_R(26) TF_R(6)
  v0 += k2; v1 += k0 + 5u;
#undef TF_R
  o0 = v0; o1 = v1;
}

__device__ __forceinline__ float erfinv_xla_f32(float x) {
  float t = __fmul_rn(x, x);
  float w = -(float)log1p(-(double)t);   // correctly-rounded f32 log1p
  float p;
  if (w < 5.0f) {
    w = __fadd_rn(w, -2.5f);
    p = 2.81022636e-08f;
    p = __fadd_rn(__fmul_rn(p, w), 3.43273939e-07f);
    p = __fadd_rn(__fmul_rn(p, w), -3.5233877e-06f);
    p = __fadd_rn(__fmul_rn(p, w), -4.39150654e-06f);
    p = __fadd_rn(__fmul_rn(p, w), 0.00021858087f);
    p = __fadd_rn(__fmul_rn(p, w), -0.00125372503f);
    p = __fadd_rn(__fmul_rn(p, w), -0.00417768164f);
    p = __fadd_rn(__fmul_rn(p, w), 0.246640727f);
    p = __fadd_rn(__fmul_rn(p, w), 1.50140941f);
  } else {
    w = __fadd_rn(__fsqrt_rn(w), -3.0f);
    p = -0.000200214257f;
    p = __fadd_rn(__fmul_rn(p, w), 0.000100950558f);
    p = __fadd_rn(__fmul_rn(p, w), 0.00134934322f);
    p = __fadd_rn(__fmul_rn(p, w), -0.00367342844f);
    p = __fadd_rn(__fmul_rn(p, w), 0.00573950773f);
    p = __fadd_rn(__fmul_rn(p, w), -0.0076224613f);
    p = __fadd_rn(__fmul_rn(p, w), 0.00943887047f);
    p = __fadd_rn(__fmul_rn(p, w), 1.00167406f);
    p = __fadd_rn(__fmul_rn(p, w), 2.83297682f);
  }
  return __fmul_rn(p, x);
}

__device__ __forceinline__ float eps_val(int t, int b) {
  uint32_t n = (uint32_t)t * 32768u + (uint32_t)b;
  uint32_t o0, o1;
  threefry2x32(0u, n, o0, o1);
  uint32_t bits = o0 ^ o1;
  const float lo    = __uint_as_float(0xBF7FFFFFu);
  const float sqrt2 = __uint_as_float(0x3FB504F3u);
  float f = __fadd_rn(__uint_as_float((bits >> 9) | 0x3F800000u), -1.0f);
  float u = __fadd_rn(__fmul_rn(f, 2.0f), lo);
  u = fmaxf(u, lo);
  return __fmul_rn(sqrt2, erfinv_xla_f32(u));
}

__device__ __forceinline__ float fexp2(float x) { return __builtin_amdgcn_exp2f(x); }
__device__ __forceinline__ float frcp(float x)  { return __builtin_amdgcn_rcpf(x); }
__device__ __forceinline__ float fexp(float x)  { return fexp2(1.442695040888963f * x); }
__device__ __forceinline__ float sigm(float x)  { return frcp(1.0f + fexp2(-1.442695040888963f * x)); }
__device__ __forceinline__ float tanhx(float x) { return 1.0f - 2.0f * frcp(1.0f + fexp2(2.885390081777926f * x)); }

// 4 lanes per element: role = tid&3 owns k in [5*role, 5*role+5) (20 gates).
// 131072 threads = 2048 waves = 2 waves/SIMD.
// launch_bounds min-waves = 1: DO NOT force a 128-VGPR cap — r1 showed the
// live set (~150 regs) spills at 128 → 4 GB scratch fetch, 2089 µs. At ~190
// VGPR the HW rounds the allocation to 256 → 2 waves/SIMD still co-resident
// (grid 512 blocks = 2 blocks/CU, LDS 2×53.7 KB = 107 KB < 160 KB).
__global__ __launch_bounds__(256, 1) void sampler_kernel(
    const float* __restrict__ mu, const float* __restrict__ log_var,
    const float* __restrict__ W_ih1, const float* __restrict__ W_hh1,
    const float* __restrict__ b_ih1, const float* __restrict__ b_hh1,
    const float* __restrict__ W_ih2, const float* __restrict__ W_hh2,
    const float* __restrict__ b_ih2, const float* __restrict__ b_hh2,
    float* __restrict__ out) {
  // role-split layouts: per-instruction only 4 distinct LDS addresses
  // (16-lane broadcast each); worst bank aliasing is 2-way (free, m136).
  __shared__ __align__(16) float sWih1T[127 * NG];  // [j][role*20 + type*5 + kl]
  __shared__ __align__(16) float sWhh1[NG * HID];   // [((role*4+type)*5+kl)][j]
  __shared__ __align__(16) float sWih2[320];        // [((role*5+kl)*2+hc)][j=0..7]
  __shared__ __align__(16) float sB1s[NG];          // [role*20 + type*5 + kl]
  __shared__ __align__(16) float sH[64 * HID];      // per-elem h exchange buffer

  const int tid = threadIdx.x;
  for (int i = tid; i < 127 * NG; i += 256) {
    int j = i / NG, q = i - j * NG;          // q = role*20 + type*5 + kl
    int ro = q / 20, rem = q - ro * 20;
    int ty = rem / 5, kl = rem - ty * 5;
    int g = ty * 20 + ro * 5 + kl;
    sWih1T[i] = W_ih1[g * 127 + j];
  }
  for (int i = tid; i < NG * HID; i += 256) {
    int j = i % HID, r = i / HID;            // r = (role*4+type)*5+kl
    int kl = r % 5, rt = r / 5;
    int ro = rt >> 2, ty = rt & 3;
    int g = ty * 20 + ro * 5 + kl;
    sWhh1[i] = W_hh1[g * HID + j];
  }
  for (int i = tid; i < 320; i += 256) {
    int j = i & 7, r = i >> 3;               // r = (role*5+kl)*2+hc
    int hc = r & 1, rk = r >> 1;
    int ro = rk / 5, kl = rk - ro * 5;
    sWih2[i] = W_ih2[j * 40 + hc * 20 + ro * 5 + kl];
  }
  if (tid < NG) {
    int ro = tid / 20, rem = tid % 20;
    int ty = rem / 5, kl = rem % 5;
    int g = ty * 20 + ro * 5 + kl;
    sB1s[tid] = b_ih1[g] + b_hh1[g];
  }
  __syncthreads();

  // tiny LSTM2 weights: uniform loads, hoisted out of the loop entirely
  float w2[16], b2s[8];
#pragma unroll
  for (int i = 0; i < 16; ++i) w2[i] = W_hh2[i];
#pragma unroll
  for (int i = 0; i < 8; ++i)  b2s[i] = b_ih2[i] + b_hh2[i];

  const int role = tid & 3;
  const int eloc = tid >> 2;
  const int elem = blockIdx.x * 64 + eloc;
  const int rbase = role * 20;
  const float* mrow = mu + (size_t)elem * LDIM;
  float* hx = &sH[eloc * HID];

  // first_input (computed identically on all 4 lanes of the group)
  float eps0 = eps_val(0, elem);
  float m0 = mrow[0];
  float fi = fmaf(eps0, fexp(0.5f * log_var[(size_t)elem * LDIM]), m0);

  // acc[i], i = type*5+kl — this lane's 20 gate accumulators.
  // Bias (b_ih1+b_hh1) folded in at init: constant across steps, the
  // prefix updates preserve it → saves 20 LDS reads + 20 adds per step.
  float acc[20];
  {
    const float4* c4 = (const float4*)&sWih1T[rbase];
    const float4* b4 = (const float4*)&sB1s[rbase];
#pragma unroll
    for (int q = 0; q < 5; ++q) {
      float4 w4 = c4[q], bb = b4[q];
      acc[4*q]   = fmaf(fi, w4.x, bb.x);
      acc[4*q+1] = fmaf(fi, w4.y, bb.y);
      acc[4*q+2] = fmaf(fi, w4.z, bb.z);
      acc[4*q+3] = fmaf(fi, w4.w, bb.w);
    }
  }

  float h[HID], c[5];
#pragma unroll
  for (int k = 0; k < HID; ++k) h[k] = 0.0f;
#pragma unroll
  for (int k = 0; k < 5; ++k) c[k] = 0.0f;
  float h2a = 0.0f, h2b = 0.0f, c2a = 0.0f, c2b = 0.0f;

  float* out_mu = out;
  float* out_lv = out + (size_t)BATCH * LDIM;
  float* out_sp = out + 2 * (size_t)BATCH * LDIM;
  const size_t rowoff = (size_t)elem * LDIM;
  if (role == 0)      out_mu[rowoff] = 0.0f;
  else if (role == 1) out_lv[rowoff] = 1.0f;
  else if (role == 2) out_sp[rowoff] = fi;

  float xm_pref = m0;     // mrow[t-1] prefetched one iteration ahead
  float eps4 = 0.0f;      // this role's eps for t = tgroup + role

  for (int t = 1; t < LDIM; ++t) {
    const int ph = (t - 1) & 3;
    float xm = xm_pref;
    xm_pref = mrow[t];                       // for next iter: mrow[(t+1)-1]
    // eps role-split: every 4th step each role computes eps(t+role);
    // consumers fetch via shuffle — bit-identical values, 4x fewer calls.
    if (ph == 0) eps4 = eps_val(t + role, elem);

    // ---- maintain acc = bias + (input cols) @ W_ih1^T  (prefix trick) ----
    if (t >= 2) {
      if (t == 2) {
        float d0 = m0 - fi;   // col 0 switches first_input -> mu[:,0]
        const float4* c04 = (const float4*)&sWih1T[rbase];
#pragma unroll
        for (int q = 0; q < 5; ++q) {
          float4 w4 = c04[q];
          acc[4*q]   = fmaf(d0, w4.x, acc[4*q]);
          acc[4*q+1] = fmaf(d0, w4.y, acc[4*q+1]);
          acc[4*q+2] = fmaf(d0, w4.z, acc[4*q+2]);
          acc[4*q+3] = fmaf(d0, w4.w, acc[4*q+3]);
        }
      }
      const float4* col4 = (const float4*)&sWih1T[(t - 1) * NG + rbase];
#pragma unroll
      for (int q = 0; q < 5; ++q) {
        float4 w4 = col4[q];
        acc[4*q]   = fmaf(xm, w4.x, acc[4*q]);
        acc[4*q+1] = fmaf(xm, w4.y, acc[4*q+1]);
        acc[4*q+2] = fmaf(xm, w4.z, acc[4*q+2]);
        acc[4*q+3] = fmaf(xm, w4.w, acc[4*q+3]);
      }
    }

    // ---- LSTM1: this lane's 5 k's (20 gates), fused LSTM2 partials ----
    // (g2 recurrent part deferred to after the butterfly — keeps only
    //  g2p[8] live across this loop, not g2i[8] as well)
    float g2p[8];
#pragma unroll
    for (int jj = 0; jj < 8; ++jj) g2p[jj] = 0.0f;

    float hn[5];
#pragma unroll
    for (int kl = 0; kl < 5; ++kl) {
      float s0 = acc[kl];
      float s1 = acc[5 + kl];
      float s2 = acc[10 + kl];
      float s3 = acc[15 + kl];
      const float4* wi = (const float4*)&sWhh1[((role * 4 + 0) * 5 + kl) * HID];
      const float4* wf = (const float4*)&sWhh1[((role * 4 + 1) * 5 + kl) * HID];
      const float4* wg = (const float4*)&sWhh1[((role * 4 + 2) * 5 + kl) * HID];
      const float4* wo = (const float4*)&sWhh1[((role * 4 + 3) * 5 + kl) * HID];
#pragma unroll
      for (int q = 0; q < 5; ++q) {
        float4 a = wi[q], bq = wf[q], cq = wg[q], dq = wo[q];
        float v0 = h[4*q], v1 = h[4*q+1], v2 = h[4*q+2], v3 = h[4*q+3];
        s0 = fmaf(v0, a.x, s0);  s0 = fmaf(v1, a.y, s0);
        s0 = fmaf(v2, a.z, s0);  s0 = fmaf(v3, a.w, s0);
        s1 = fmaf(v0, bq.x, s1); s1 = fmaf(v1, bq.y, s1);
        s1 = fmaf(v2, bq.z, s1); s1 = fmaf(v3, bq.w, s1);
        s2 = fmaf(v0, cq.x, s2); s2 = fmaf(v1, cq.y, s2);
        s2 = fmaf(v2, cq.z, s2); s2 = fmaf(v3, cq.w, s2);
        s3 = fmaf(v0, dq.x, s3); s3 = fmaf(v1, dq.y, s3);
        s3 = fmaf(v2, dq.z, s3); s3 = fmaf(v3, dq.w, s3);
      }
      float ik = sigm(s0), fk = sigm(s1), gk = tanhx(s2), ok = sigm(s3);
      float cn = fmaf(fk, c[kl], ik * gk);
      c[kl] = cn;
      float hk = ok * tanhx(cn);
      hn[kl] = hk;
      float lh = (hk >= 0.0f) ? hk : 0.01f * hk;
      float lc = (cn >= 0.0f) ? cn : 0.01f * cn;
      const float4* uu = (const float4*)&sWih2[((role * 5 + kl) * 2 + 0) * 8];
      const float4* vv = (const float4*)&sWih2[((role * 5 + kl) * 2 + 1) * 8];
      float4 u0 = uu[0], u1 = uu[1], v0 = vv[0], v1 = vv[1];
      g2p[0] = fmaf(lh, u0.x, g2p[0]); g2p[1] = fmaf(lh, u0.y, g2p[1]);
      g2p[2] = fmaf(lh, u0.z, g2p[2]); g2p[3] = fmaf(lh, u0.w, g2p[3]);
      g2p[4] = fmaf(lh, u1.x, g2p[4]); g2p[5] = fmaf(lh, u1.y, g2p[5]);
      g2p[6] = fmaf(lh, u1.z, g2p[6]); g2p[7] = fmaf(lh, u1.w, g2p[7]);
      g2p[0] = fmaf(lc, v0.x, g2p[0]); g2p[1] = fmaf(lc, v0.y, g2p[1]);
      g2p[2] = fmaf(lc, v0.z, g2p[2]); g2p[3] = fmaf(lc, v0.w, g2p[3]);
      g2p[4] = fmaf(lc, v1.x, g2p[4]); g2p[5] = fmaf(lc, v1.y, g2p[5]);
      g2p[6] = fmaf(lc, v1.z, g2p[6]); g2p[7] = fmaf(lc, v1.w, g2p[7]);
    }

    // ---- h all-gather via wave-synchronous LDS (group of 4 lanes is
    // always inside one wave; compiler inserts lgkmcnt, no barrier) ----
#pragma unroll
    for (int kl = 0; kl < 5; ++kl) hx[role * 5 + kl] = hn[kl];
    {
      const float4* h4 = (const float4*)hx;
#pragma unroll
      for (int q = 0; q < 5; ++q) {
        float4 hv = h4[q];
        h[4*q] = hv.x; h[4*q+1] = hv.y; h[4*q+2] = hv.z; h[4*q+3] = hv.w;
      }
    }

    // ---- LSTM2 gates: 4-lane butterfly reduce + recurrent part ----
    float g2[8];
#pragma unroll
    for (int jj = 0; jj < 8; ++jj) {
      float v = g2p[jj];
      v += __shfl_xor(v, 1, 64);
      v += __shfl_xor(v, 2, 64);
      g2[jj] = fmaf(h2a, w2[2*jj], fmaf(h2b, w2[2*jj+1], b2s[jj])) + v;
    }

    float i20 = sigm(g2[0]), i21 = sigm(g2[1]);
    float f20 = sigm(g2[2]), f21 = sigm(g2[3]);
    float t20 = tanhx(g2[4]), t21 = tanhx(g2[5]);
    float o20 = sigm(g2[6]), o21 = sigm(g2[7]);
    c2a = fmaf(f20, c2a, i20 * t20);
    c2b = fmaf(f21, c2b, i21 * t21);
    h2a = o20 * tanhx(c2a);
    h2b = o21 * tanhx(c2b);

    // ---- sample + stores (role-split) ----
    float eps_t = __shfl(eps4, (tid & 60) | ph, 64);
    float sp = fmaf(eps_t, fexp(0.5f * h2b), h2a);
    if (role == 0)      out_mu[rowoff + t] = h2a;
    else if (role == 1) out_lv[rowoff + t] = h2b;
    else if (role == 2) out_sp[rowoff + t] = sp;
  }
}

extern "C" void kernel_launch(void* const* d_in, const int* in_sizes, int n_in,
                              void* d_out, int out_size, void* d_ws, size_t ws_size,
                              hipStream_t stream) {
  (void)in_sizes; (void)n_in; (void)d_ws; (void)ws_size; (void)out_size;
  const float* mu      = (const float*)d_in[0];
  const float* log_var = (const float*)d_in[1];
  const float* W_ih1   = (const float*)d_in[2];
  const float* W_hh1   = (const float*)d_in[3];
  const float* b_ih1   = (const float*)d_in[4];
  const float* b_hh1   = (const float*)d_in[5];
  const float* W_ih2   = (const float*)d_in[6];
  const float* W_hh2   = (const float*)d_in[7];
  const float* b_ih2   = (const float*)d_in[8];
  const float* b_hh2   = (const float*)d_in[9];
  float* out = (float*)d_out;

  dim3 grid(BATCH / 64), block(256);   // 4 lanes per element, 512 blocks = 2/CU
  sampler_kernel<<<grid, block, 0, stream>>>(mu, log_var, W_ih1, W_hh1, b_ih1,
                                             b_hh1, W_ih2, W_hh2, b_ih2, b_hh2, out);
}

// Round 3
// 770.833 us; speedup vs baseline: 2.7106x; 1.4143x over previous
//
#include <hip/hip_runtime.h>
#include <stdint.h>
#include <math.h>

#define BATCH 32768
#define LDIM 128
#define HID 20

// =====================================================================
// eps: jax.random.normal(key(42), (128,32768), f32), partitionable
// threefry (counters (0,n), output o0^o1) — VERIFIED PASSING (r4/r5,
// absmax 0.0156 = 1 bf16 ulp). Do not touch.
// =====================================================================

__device__ __forceinline__ void threefry2x32(uint32_t x0, uint32_t x1,
                                             uint32_t& o0, uint32_t& o1) {
  const uint32_t k0 = 0u, k1 = 42u;
  const uint32_t k2 = k0 ^ k1 ^ 0x1BD11BDAu;
  uint32_t v0 = x0 + k0, v1 = x1 + k1;
#define TF_R(r) { v0 += v1; v1 = (v1 << (r)) | (v1 >> (32 - (r))); v1 ^= v0; }
  TF_R(13) TF_R(15) TF_R(26) TF_R(6)
  v0 += k1; v1 += k2 + 1u;
  TF_R(17) TF_R(29) TF_R(16) TF_R(24)
  v0 += k2; v1 += k0 + 2u;
  TF_R(13) TF_R(15) TF_R(26) TF_R(6)
  v0 += k0; v1 += k1 + 3u;
  TF_R(17) TF_R(29) TF_R(16) TF_R(24)
  v0 += k1; v1 += k2 + 4u;
  TF_R(13) TF_R(15) TF_R(26) TF_R(6)
  v0 += k2; v1 += k0 + 5u;
#undef TF_R
  o0 = v0; o1 = v1;
}

__device__ __forceinline__ float erfinv_xla_f32(float x) {
  float t = __fmul_rn(x, x);
  float w = -(float)log1p(-(double)t);   // correctly-rounded f32 log1p
  float p;
  if (w < 5.0f) {
    w = __fadd_rn(w, -2.5f);
    p = 2.81022636e-08f;
    p = __fadd_rn(__fmul_rn(p, w), 3.43273939e-07f);
    p = __fadd_rn(__fmul_rn(p, w), -3.5233877e-06f);
    p = __fadd_rn(__fmul_rn(p, w), -4.39150654e-06f);
    p = __fadd_rn(__fmul_rn(p, w), 0.00021858087f);
    p = __fadd_rn(__fmul_rn(p, w), -0.00125372503f);
    p = __fadd_rn(__fmul_rn(p, w), -0.00417768164f);
    p = __fadd_rn(__fmul_rn(p, w), 0.246640727f);
    p = __fadd_rn(__fmul_rn(p, w), 1.50140941f);
  } else {
    w = __fadd_rn(__fsqrt_rn(w), -3.0f);
    p = -0.000200214257f;
    p = __fadd_rn(__fmul_rn(p, w), 0.000100950558f);
    p = __fadd_rn(__fmul_rn(p, w), 0.00134934322f);
    p = __fadd_rn(__fmul_rn(p, w), -0.00367342844f);
    p = __fadd_rn(__fmul_rn(p, w), 0.00573950773f);
    p = __fadd_rn(__fmul_rn(p, w), -0.0076224613f);
    p = __fadd_rn(__fmul_rn(p, w), 0.00943887047f);
    p = __fadd_rn(__fmul_rn(p, w), 1.00167406f);
    p = __fadd_rn(__fmul_rn(p, w), 2.83297682f);
  }
  return __fmul_rn(p, x);
}

__device__ __forceinline__ float eps_val(int t, int b) {
  uint32_t n = (uint32_t)t * 32768u + (uint32_t)b;
  uint32_t o0, o1;
  threefry2x32(0u, n, o0, o1);
  uint32_t bits = o0 ^ o1;
  const float lo    = __uint_as_float(0xBF7FFFFFu);
  const float sqrt2 = __uint_as_float(0x3FB504F3u);
  float f = __fadd_rn(__uint_as_float((bits >> 9) | 0x3F800000u), -1.0f);
  float u = __fadd_rn(__fmul_rn(f, 2.0f), lo);
  u = fmaxf(u, lo);
  return __fmul_rn(sqrt2, erfinv_xla_f32(u));
}

__device__ __forceinline__ float fexp2(float x) { return __builtin_amdgcn_exp2f(x); }
__device__ __forceinline__ float frcp(float x)  { return __builtin_amdgcn_rcpf(x); }
__device__ __forceinline__ float fexp(float x)  { return fexp2(1.442695040888963f * x); }
__device__ __forceinline__ float sigm(float x)  { return frcp(1.0f + fexp2(-1.442695040888963f * x)); }
__device__ __forceinline__ float tanhx(float x) { return 1.0f - 2.0f * frcp(1.0f + fexp2(2.885390081777926f * x)); }

// V4: role-per-WAVE. Block = 4 waves × 64 lanes; wave w = role w handles
// gates {ty*20 + w*5 + kl} for 64 elements (1 element per lane). All weight
// addresses are wave-uniform → scalar s_load into SGPRs → the dot is
// v_fmac(v, s, v): zero LDS traffic for weights (r2 burned ~660 µs/CU on
// 130 ds_read_b128/wave-iter). LDS keeps only the per-step h / g2-partial /
// h2 / eps exchanges (~20 instr/wave-iter), one __syncthreads per step over
// double buffers. VGPR target ≤128 (per-lane state ~70) so 2 blocks/CU
// co-reside (r2 at 192 VGPR stayed at 1 block/CU = 11.9% occupancy).
__global__ __launch_bounds__(256, 2) void sampler_kernel(
    const float* __restrict__ mu, const float* __restrict__ log_var,
    const float* __restrict__ W_ih1, const float* __restrict__ W_hh1,
    const float* __restrict__ b_ih1, const float* __restrict__ b_hh1,
    const float* __restrict__ W_ih2, const float* __restrict__ W_hh2,
    const float* __restrict__ b_ih2, const float* __restrict__ b_hh2,
    float* __restrict__ out) {
  // exchange buffers, all lane-stride-4B (conflict-free), double-buffered
  __shared__ float hbuf[2][HID][64];     // [buf][k][elem]  h1 state
  __shared__ float gbuf[2][8][4][64];    // [buf][j][wave][elem]  g2 partials
  __shared__ float h2buf[2][2][64];      // [buf][a/b][elem]
  __shared__ float epsbuf[2][4][64];     // [group&1][slot][elem] eps ring

  const int tid  = threadIdx.x;
  const int lane = tid & 63;
  const int wv   = __builtin_amdgcn_readfirstlane(tid >> 6);  // uniform!
  const int wv5  = wv * 5;
  const int elem = blockIdx.x * 64 + lane;
  const float* mrow = mu + (size_t)elem * LDIM;

  if (tid < 128) h2buf[0][tid >> 6][tid & 63] = 0.0f;  // h2(0) = 0

  // first_input (replicated on all 4 waves; bit-identical)
  float eps0 = eps_val(0, elem);
  float m0 = mrow[0];
  float fi = fmaf(eps0, fexp(0.5f * log_var[(size_t)elem * LDIM]), m0);

  // acc[i], i = ty*5+kl — this wave's 20 gate accumulators, bias folded.
  float acc[20];
#pragma unroll
  for (int i = 0; i < 20; ++i) {
    const int ty = i / 5, kl = i % 5;
    const int g = ty * 20 + wv5 + kl;               // uniform
    acc[i] = fmaf(fi, W_ih1[g * 127], b_ih1[g] + b_hh1[g]);
  }

  float h[HID];
#pragma unroll
  for (int j = 0; j < HID; ++j) h[j] = 0.0f;
  float cst[5];
#pragma unroll
  for (int k = 0; k < 5; ++k) cst[k] = 0.0f;
  float c2 = 0.0f;                                   // wave0: c2a, wave1: c2b

  float* out_mu = out;
  float* out_lv = out + (size_t)BATCH * LDIM;
  float* out_sp = out + 2 * (size_t)BATCH * LDIM;
  const size_t rowoff = (size_t)elem * LDIM;
  if (wv == 2)      out_sp[rowoff] = fi;
  else if (wv == 3) { out_mu[rowoff] = 0.0f; out_lv[rowoff] = 1.0f; }

  float xm_pref = m0;

  for (int t = 1; t < LDIM; ++t) {
    const int buf = t & 1;
    float xm = xm_pref;
    xm_pref = mrow[t];

    // ---- eps ring: every 4 steps, wave w computes eps((t-1)+w) ----
    if (((t - 1) & 3) == 0) {
      const int e0 = t - 1;
      epsbuf[(e0 >> 2) & 1][wv][lane] = eps_val(e0 + wv, elem);
    }

    // ---- maintain acc = bias + (input cols) @ W_ih1^T  (prefix trick) ----
    if (t >= 2) {
      if (t == 2) {
        float d0 = m0 - fi;   // col 0 switches first_input -> mu[:,0]
#pragma unroll
        for (int i = 0; i < 20; ++i) {
          const int ty = i / 5, kl = i % 5;
          const int g = ty * 20 + wv5 + kl;
          acc[i] = fmaf(d0, W_ih1[g * 127], acc[i]);
        }
      }
#pragma unroll
      for (int i = 0; i < 20; ++i) {
        const int ty = i / 5, kl = i % 5;
        const int g = ty * 20 + wv5 + kl;
        acc[i] = fmaf(xm, W_ih1[g * 127 + (t - 1)], acc[i]);  // s_load col
      }
    }

    // ---- LSTM1 gates (SGPR weights), cell, fused LSTM2 partials ----
    float g2p[8];
#pragma unroll
    for (int j = 0; j < 8; ++j) g2p[j] = 0.0f;

#pragma unroll
    for (int kl = 0; kl < 5; ++kl) {
      float s0 = acc[kl], s1 = acc[5 + kl], s2 = acc[10 + kl], s3 = acc[15 + kl];
      const float* wr0 = W_hh1 + (size_t)(     wv5 + kl) * HID;
      const float* wr1 = W_hh1 + (size_t)(20 + wv5 + kl) * HID;
      const float* wr2 = W_hh1 + (size_t)(40 + wv5 + kl) * HID;
      const float* wr3 = W_hh1 + (size_t)(60 + wv5 + kl) * HID;
#pragma unroll
      for (int j = 0; j < HID; ++j) {
        const float hj = h[j];
        s0 = fmaf(hj, wr0[j], s0);
        s1 = fmaf(hj, wr1[j], s1);
        s2 = fmaf(hj, wr2[j], s2);
        s3 = fmaf(hj, wr3[j], s3);
      }
      float ik = sigm(s0), fk = sigm(s1), gk = tanhx(s2), ok = sigm(s3);
      float cn = fmaf(fk, cst[kl], ik * gk);
      cst[kl] = cn;
      float hk = ok * tanhx(cn);
      hbuf[buf][wv5 + kl][lane] = hk;                // stride-4B, free
      float lh = (hk >= 0.0f) ? hk : 0.01f * hk;
      float lc = (cn >= 0.0f) ? cn : 0.01f * cn;
      const int k = wv5 + kl;                        // uniform
#pragma unroll
      for (int j = 0; j < 8; ++j) g2p[j] = fmaf(lh, W_ih2[j * 40 + k], g2p[j]);
#pragma unroll
      for (int j = 0; j < 8; ++j) g2p[j] = fmaf(lc, W_ih2[j * 40 + 20 + k], g2p[j]);
    }

#pragma unroll
    for (int j = 0; j < 8; ++j) gbuf[buf][j][wv][lane] = g2p[j];

    __syncthreads();   // one barrier per step; all exchanges double-buffered

    // ---- next-step h (all waves) ----
#pragma unroll
    for (int j = 0; j < HID; ++j) h[j] = hbuf[buf][j][lane];

    const float h2a_p = h2buf[buf ^ 1][0][lane];     // h2(t-1)
    const float h2b_p = h2buf[buf ^ 1][1][lane];

    if (wv <= 1) {
      // waves 0/1: reduce partials + LSTM2 cell for unit wv
      float g2[4];
#pragma unroll
      for (int jj = 0; jj < 4; ++jj) {
        const int j = 2 * jj + wv;
        float p0 = gbuf[buf][j][0][lane];
        float p1 = gbuf[buf][j][1][lane];
        float p2 = gbuf[buf][j][2][lane];
        float p3 = gbuf[buf][j][3][lane];
        float v = (p0 + p1) + (p2 + p3);             // matches r2 butterfly
        g2[jj] = fmaf(h2a_p, W_hh2[2 * j],
                      fmaf(h2b_p, W_hh2[2 * j + 1], b_ih2[j] + b_hh2[j])) + v;
      }
      float i2 = sigm(g2[0]), f2 = sigm(g2[1]), tg = tanhx(g2[2]), o2 = sigm(g2[3]);
      c2 = fmaf(f2, c2, i2 * tg);
      float h2n = o2 * tanhx(c2);
      h2buf[buf][wv][lane] = h2n;
    } else if (wv == 2) {
      if (t >= 2) {                                  // sample for col t-1
        const int e = t - 1;
        float eps_t = epsbuf[(e >> 2) & 1][e & 3][lane];
        out_sp[rowoff + e] = fmaf(eps_t, fexp(0.5f * h2b_p), h2a_p);
      }
    } else {
      if (t >= 2) {                                  // mu/lv for col t-1
        out_mu[rowoff + (t - 1)] = h2a_p;
        out_lv[rowoff + (t - 1)] = h2b_p;
      }
    }
  }

  // ---- drain col 127 ----
  __syncthreads();
  const float h2a_f = h2buf[1][0][lane];             // t=127 wrote buf 1
  const float h2b_f = h2buf[1][1][lane];
  if (wv == 2) {
    float eps_t = epsbuf[(127 >> 2) & 1][127 & 3][lane];  // group 31, buf 1
    out_sp[rowoff + 127] = fmaf(eps_t, fexp(0.5f * h2b_f), h2a_f);
  } else if (wv == 3) {
    out_mu[rowoff + 127] = h2a_f;
    out_lv[rowoff + 127] = h2b_f;
  }
}

extern "C" void kernel_launch(void* const* d_in, const int* in_sizes, int n_in,
                              void* d_out, int out_size, void* d_ws, size_t ws_size,
                              hipStream_t stream) {
  (void)in_sizes; (void)n_in; (void)d_ws; (void)ws_size; (void)out_size;
  const float* mu      = (const float*)d_in[0];
  const float* log_var = (const float*)d_in[1];
  const float* W_ih1   = (const float*)d_in[2];
  const float* W_hh1   = (const float*)d_in[3];
  const float* b_ih1   = (const float*)d_in[4];
  const float* b_hh1   = (const float*)d_in[5];
  const float* W_ih2   = (const float*)d_in[6];
  const float* W_hh2   = (const float*)d_in[7];
  const float* b_ih2   = (const float*)d_in[8];
  const float* b_hh2   = (const float*)d_in[9];
  float* out = (float*)d_out;

  dim3 grid(BATCH / 64), block(256);   // 1 elem/lane, 4 role-waves, 2 blocks/CU
  sampler_kernel<<<grid, block, 0, stream>>>(mu, log_var, W_ih1, W_hh1, b_ih1,
                                             b_hh1, W_ih2, W_hh2, b_ih2, b_hh2, out);
}